// Round 7
// baseline (102.459 us; speedup 1.0000x reference)
//
#include <hip/hip_runtime.h>

typedef unsigned int u32;
typedef unsigned short u16;
typedef _Float16 f16;
typedef f16 f16x8 __attribute__((ext_vector_type(8)));
typedef float f32x4 __attribute__((ext_vector_type(4)));

#define NTH 256
#define SH1 72   // K1 h1buf row stride in f16

__device__ __forceinline__ u32 pack2(float a, float b) {
    f16 fa = (f16)a, fb = (f16)b;
    return (u32)__builtin_bit_cast(u16, fa) | ((u32)__builtin_bit_cast(u16, fb) << 16);
}

// ---------------- K1: conv+pool (round-6 validated structure) ----------------
// One 256-thread block per row i; MFMA conv2; writes pooled[i][0..127] as f16.
__global__ __launch_bounds__(NTH) void pool_kernel(
    const float* __restrict__ s,
    const float* __restrict__ w1g, const float* __restrict__ b1g,
    const float* __restrict__ w2g, const float* __restrict__ b2g,
    u16* __restrict__ pooled)
{
    __shared__ float4 acts[1024];
    __shared__ int    actj[1024];
    __shared__ f16    h1buf[16][SH1];
    __shared__ float  w1s[320];
    __shared__ float  b1s[64];
    __shared__ int    cnt;

    const int tid  = threadIdx.x;
    const int lane = tid & 63;
    const int wave = tid >> 6;
    const int i    = blockIdx.x;

    if (tid == 0) cnt = 0;
    for (int q = tid; q < 320; q += NTH) w1s[q] = w1g[q];
    if (tid < 64) b1s[tid] = b1g[tid];
    __syncthreads();

    const float4 si = ((const float4*)s)[i];

    #pragma unroll
    for (int p = 0; p < 4; ++p) {
        const int j = p * NTH + tid;
        float4 sj = ((const float4*)s)[j];
        float dx = si.x - sj.x, dy = si.y - sj.y;
        if (dx * dx + dy * dy < 0.25f) {
            int slot = atomicAdd(&cnt, 1);
            acts[slot] = sj;
            actj[slot] = j;
        }
    }
    __syncthreads();
    const int n_act = cnt;

    // w2 B-fragments: wave owns channels 32w..32w+31 as two 16-wide N-tiles
    const int n_base = wave * 32;
    const int ncol   = lane & 15;
    const int kq     = lane >> 4;
    f16x8 bfrag[2][2];
    float b2r[2];
    #pragma unroll
    for (int tile = 0; tile < 2; ++tile) {
        const int n = n_base + tile * 16 + ncol;
        b2r[tile] = b2g[n];
        #pragma unroll
        for (int t = 0; t < 2; ++t) {
            const float* wp = w2g + n * 64 + t * 32 + kq * 8;
            float4 lo = ((const float4*)wp)[0];
            float4 hi = ((const float4*)wp)[1];
            f16x8 b;
            b[0] = (f16)lo.x; b[1] = (f16)lo.y; b[2] = (f16)lo.z; b[3] = (f16)lo.w;
            b[4] = (f16)hi.x; b[5] = (f16)hi.y; b[6] = (f16)hi.z; b[7] = (f16)hi.w;
            bfrag[tile][t] = b;
        }
    }

    float mtile[2] = {0.0f, 0.0f};

    for (int gbase = 0; gbase < n_act; gbase += 16) {
        #pragma unroll
        for (int it = 0; it < 2; ++it) {
            const int idx = it * NTH + tid;
            const int p = idx >> 5, c2 = idx & 31;
            if (gbase + p < n_act) {
                const float4 sj = acts[gbase + p];
                const float x0 = si.x - sj.x, x1 = si.y - sj.y;
                const float x2 = si.z - sj.z, x3 = si.w - sj.w;
                const float x4 = (actj[gbase + p] == i) ? 1.0f : 0.0f;
                const int c = c2 * 2;
                const float* wa = &w1s[c * 5];
                float ha = b1s[c];
                ha = fmaf(wa[0], x0, ha); ha = fmaf(wa[1], x1, ha);
                ha = fmaf(wa[2], x2, ha); ha = fmaf(wa[3], x3, ha);
                ha = fmaf(wa[4], x4, ha);
                const float* wb = &w1s[c * 5 + 5];
                float hb = b1s[c + 1];
                hb = fmaf(wb[0], x0, hb); hb = fmaf(wb[1], x1, hb);
                hb = fmaf(wb[2], x2, hb); hb = fmaf(wb[3], x3, hb);
                hb = fmaf(wb[4], x4, hb);
                *(u32*)&h1buf[p][c2 * 2] = pack2(fmaxf(ha, 0.0f), fmaxf(hb, 0.0f));
            }
        }
        __syncthreads();

        f16x8 afr[2];
        #pragma unroll
        for (int t = 0; t < 2; ++t)
            afr[t] = *(const f16x8*)&h1buf[ncol][t * 32 + kq * 8];

        #pragma unroll
        for (int tile = 0; tile < 2; ++tile) {
            f32x4 acc = {0.0f, 0.0f, 0.0f, 0.0f};
            acc = __builtin_amdgcn_mfma_f32_16x16x32_f16(afr[0], bfrag[tile][0], acc, 0, 0, 0);
            acc = __builtin_amdgcn_mfma_f32_16x16x32_f16(afr[1], bfrag[tile][1], acc, 0, 0, 0);
            #pragma unroll
            for (int r = 0; r < 4; ++r) {
                const bool valid = (gbase + kq * 4 + r) < n_act;
                const float v = acc[r] + b2r[tile];
                mtile[tile] = valid ? fmaxf(mtile[tile], v) : mtile[tile];
            }
        }
        __syncthreads();
    }

    #pragma unroll
    for (int tile = 0; tile < 2; ++tile) {
        float m = mtile[tile];
        m = fmaxf(m, __shfl_xor(m, 16));
        m = fmaxf(m, __shfl_xor(m, 32));
        if (lane < 16) {
            f16 h = (f16)m;
            pooled[i * 128 + n_base + tile * 16 + lane] = __builtin_bit_cast(u16, h);
        }
    }
}

// ---------------- K2: batched MFMA head ----------------
// 32 blocks x 32 rows. Weights staged once/block into LDS (f16, stride-padded).
// Fragment convention (verified in K1/r6): A and B frags both read 8 contiguous
// k-elements at row (lane&15), k-offset (lane>>4)*8 + 32*kstep; C lands at
// [m = kq*4+r][n = lane&15 (+tile*16)].
__global__ __launch_bounds__(NTH) void head_kernel(
    const float* __restrict__ s,    const float* __restrict__ g,
    const float* __restrict__ fc1w, const float* __restrict__ fc1b,
    const float* __restrict__ fc2w, const float* __restrict__ fc2b,
    const float* __restrict__ fc3w, const float* __restrict__ fc3b,
    const float* __restrict__ fc4w, const float* __restrict__ fc4b,
    const u16* __restrict__ pooled,
    float2* __restrict__ out)
{
    __shared__ f16 feat[32][168];   // K=160 logical (132 real + zeros)
    __shared__ f16 w1s[64][168];
    __shared__ f16 z1s[32][72];     // K=64
    __shared__ f16 w2s[128][72];
    __shared__ f16 z2s[32][136];    // K=128
    __shared__ f16 w3s[64][136];
    __shared__ f16 z3s[32][72];
    __shared__ f16 w4s[16][72];
    __shared__ float b1h[64], b2h[128], b3h[64], b4h[4];
    __shared__ float kbuf[32][4];

    const int tid  = threadIdx.x;
    const int lane = tid & 63;
    const int wave = tid >> 6;
    const int r0   = blockIdx.x * 32;

    // ---- staging (f32 -> f16 pairs) ----
    for (int slot = tid; slot < 64 * 66; slot += NTH) {        // fc1w 64x132
        int n = slot / 66, kp = slot % 66;
        float2 v = *(const float2*)(fc1w + n * 132 + kp * 2);
        *(u32*)&w1s[n][kp * 2] = pack2(v.x, v.y);
    }
    for (int slot = tid; slot < 128 * 32; slot += NTH) {       // fc2w 128x64
        int n = slot / 32, kp = slot % 32;
        float2 v = *(const float2*)(fc2w + n * 64 + kp * 2);
        *(u32*)&w2s[n][kp * 2] = pack2(v.x, v.y);
    }
    for (int slot = tid; slot < 64 * 64; slot += NTH) {        // fc3w 64x128
        int n = slot / 64, kp = slot % 64;
        float2 v = *(const float2*)(fc3w + n * 128 + kp * 2);
        *(u32*)&w3s[n][kp * 2] = pack2(v.x, v.y);
    }
    for (int slot = tid; slot < 4 * 32; slot += NTH) {         // fc4w 4x64
        int n = slot / 32, kp = slot % 32;
        float2 v = *(const float2*)(fc4w + n * 64 + kp * 2);
        *(u32*)&w4s[n][kp * 2] = pack2(v.x, v.y);
    }
    for (int slot = tid; slot < 12 * 32; slot += NTH) {        // zero w4s rows 4..15
        int n = 4 + slot / 32, kp = slot % 32;
        *(u32*)&w4s[n][kp * 2] = 0;
    }
    for (int slot = tid; slot < 32 * 64; slot += NTH) {        // pooled (already f16)
        int r = slot / 64, kp = slot % 64;
        *(u32*)&feat[r][kp * 2] = ((const u32*)(pooled + (r0 + r) * 128))[kp];
    }
    if (tid < 32) {                                            // feat[128..131] = sg|v
        int r = r0 + tid;
        float4 sv = ((const float4*)s)[r];
        float2 gv = ((const float2*)g)[r];
        *(u32*)&feat[tid][128] = pack2(sv.x - gv.x, sv.y - gv.y);
        *(u32*)&feat[tid][130] = pack2(sv.z, sv.w);
    }
    for (int slot = tid; slot < 32 * 14; slot += NTH) {        // zero feat[132..159]
        int r = slot / 14, kp = slot % 14;
        *(u32*)&feat[r][132 + kp * 2] = 0;
    }
    for (int slot = tid; slot < 64 * 14; slot += NTH) {        // zero w1s[132..159]
        int n = slot / 14, kp = slot % 14;
        *(u32*)&w1s[n][132 + kp * 2] = 0;
    }
    if (tid < 64)  b1h[tid] = fc1b[tid];
    if (tid < 128) b2h[tid] = fc2b[tid];
    if (tid < 64)  b3h[tid] = fc3b[tid];
    if (tid < 4)   b4h[tid] = fc4b[tid];
    __syncthreads();

    const int mt = wave >> 1, nh = wave & 1;
    const int m0 = mt * 16;
    const int lr = lane & 15, kq = lane >> 4;

    // ---- fc1: 160(K) -> 64, this wave: 2 of 4 N-tiles ----
    {
        f16x8 a[5];
        #pragma unroll
        for (int ks = 0; ks < 5; ++ks)
            a[ks] = *(const f16x8*)&feat[m0 + lr][ks * 32 + kq * 8];
        #pragma unroll
        for (int nt = 0; nt < 2; ++nt) {
            const int ntile = nh * 2 + nt;
            f32x4 acc = {0.0f, 0.0f, 0.0f, 0.0f};
            #pragma unroll
            for (int ks = 0; ks < 5; ++ks) {
                f16x8 b = *(const f16x8*)&w1s[ntile * 16 + lr][ks * 32 + kq * 8];
                acc = __builtin_amdgcn_mfma_f32_16x16x32_f16(a[ks], b, acc, 0, 0, 0);
            }
            const int n = ntile * 16 + lr;
            const float bn = b1h[n];
            #pragma unroll
            for (int r = 0; r < 4; ++r)
                z1s[m0 + kq * 4 + r][n] = (f16)fmaxf(acc[r] + bn, 0.0f);
        }
    }
    __syncthreads();

    // ---- fc2: 64 -> 128, this wave: 4 of 8 N-tiles ----
    {
        f16x8 a[2];
        #pragma unroll
        for (int ks = 0; ks < 2; ++ks)
            a[ks] = *(const f16x8*)&z1s[m0 + lr][ks * 32 + kq * 8];
        #pragma unroll
        for (int nt = 0; nt < 4; ++nt) {
            const int ntile = nh * 4 + nt;
            f32x4 acc = {0.0f, 0.0f, 0.0f, 0.0f};
            #pragma unroll
            for (int ks = 0; ks < 2; ++ks) {
                f16x8 b = *(const f16x8*)&w2s[ntile * 16 + lr][ks * 32 + kq * 8];
                acc = __builtin_amdgcn_mfma_f32_16x16x32_f16(a[ks], b, acc, 0, 0, 0);
            }
            const int n = ntile * 16 + lr;
            const float bn = b2h[n];
            #pragma unroll
            for (int r = 0; r < 4; ++r)
                z2s[m0 + kq * 4 + r][n] = (f16)fmaxf(acc[r] + bn, 0.0f);
        }
    }
    __syncthreads();

    // ---- fc3: 128 -> 64, this wave: 2 of 4 N-tiles ----
    {
        f16x8 a[4];
        #pragma unroll
        for (int ks = 0; ks < 4; ++ks)
            a[ks] = *(const f16x8*)&z2s[m0 + lr][ks * 32 + kq * 8];
        #pragma unroll
        for (int nt = 0; nt < 2; ++nt) {
            const int ntile = nh * 2 + nt;
            f32x4 acc = {0.0f, 0.0f, 0.0f, 0.0f};
            #pragma unroll
            for (int ks = 0; ks < 4; ++ks) {
                f16x8 b = *(const f16x8*)&w3s[ntile * 16 + lr][ks * 32 + kq * 8];
                acc = __builtin_amdgcn_mfma_f32_16x16x32_f16(a[ks], b, acc, 0, 0, 0);
            }
            const int n = ntile * 16 + lr;
            const float bn = b3h[n];
            #pragma unroll
            for (int r = 0; r < 4; ++r)
                z3s[m0 + kq * 4 + r][n] = (f16)fmaxf(acc[r] + bn, 0.0f);
        }
    }
    __syncthreads();

    // ---- fc4: 64 -> 4 (one padded N-tile) + sigmoid gain ----
    {
        f16x8 a0 = *(const f16x8*)&z3s[m0 + lr][kq * 8];
        f16x8 a1 = *(const f16x8*)&z3s[m0 + lr][32 + kq * 8];
        f16x8 b0 = *(const f16x8*)&w4s[lr][kq * 8];
        f16x8 b1 = *(const f16x8*)&w4s[lr][32 + kq * 8];
        f32x4 acc = {0.0f, 0.0f, 0.0f, 0.0f};
        acc = __builtin_amdgcn_mfma_f32_16x16x32_f16(a0, b0, acc, 0, 0, 0);
        acc = __builtin_amdgcn_mfma_f32_16x16x32_f16(a1, b1, acc, 0, 0, 0);
        if (nh == 0 && lr < 4) {
            const float bn = b4h[lr];
            #pragma unroll
            for (int r = 0; r < 4; ++r)
                kbuf[m0 + kq * 4 + r][lr] =
                    2.0f / (1.0f + expf(-(acc[r] + bn))) - 1.0f;
        }
    }
    __syncthreads();

    if (tid < 32) {
        int r = r0 + tid;
        float4 sv = ((const float4*)s)[r];
        float2 gv = ((const float2*)g)[r];
        float sgx = sv.x - gv.x, sgy = sv.y - gv.y;
        float ax = -(kbuf[tid][0] * sgx + kbuf[tid][1] * sv.z);
        float ay = -(kbuf[tid][2] * sgy + kbuf[tid][3] * sv.w);
        out[r] = make_float2(ax, ay);
    }
}

extern "C" void kernel_launch(void* const* d_in, const int* in_sizes, int n_in,
                              void* d_out, int out_size, void* d_ws, size_t ws_size,
                              hipStream_t stream) {
    const float* s    = (const float*)d_in[0];
    const float* g    = (const float*)d_in[1];
    const float* c1w  = (const float*)d_in[2];
    const float* c1b  = (const float*)d_in[3];
    const float* c2w  = (const float*)d_in[4];
    const float* c2b  = (const float*)d_in[5];
    const float* fc1w = (const float*)d_in[6];
    const float* fc1b = (const float*)d_in[7];
    const float* fc2w = (const float*)d_in[8];
    const float* fc2b = (const float*)d_in[9];
    const float* fc3w = (const float*)d_in[10];
    const float* fc3b = (const float*)d_in[11];
    const float* fc4w = (const float*)d_in[12];
    const float* fc4b = (const float*)d_in[13];

    u16* pooled = (u16*)d_ws;        // 1024x128 f16 = 256 KB
    float2* out = (float2*)d_out;

    pool_kernel<<<1024, NTH, 0, stream>>>(s, c1w, c1b, c2w, c2b, pooled);
    head_kernel<<<32, NTH, 0, stream>>>(s, g, fc1w, fc1b, fc2w, fc2b,
                                        fc3w, fc3b, fc4w, fc4b, pooled, out);
}

// Round 8
// 98.360 us; speedup vs baseline: 1.0417x; 1.0417x over previous
//
#include <hip/hip_runtime.h>

typedef unsigned int u32;
typedef unsigned short u16;
typedef _Float16 f16;
typedef f16 f16x8 __attribute__((ext_vector_type(8)));
typedef float f32x4 __attribute__((ext_vector_type(4)));

#define NTH 512
#define SH1 72   // h1buf row stride in f16 (144 B = 16*9: keeps b128 reads aligned, <=2-way banks)

__device__ __forceinline__ u32 pack2(float a, float b) {
    f16 fa = (f16)a, fb = (f16)b;
    return (u32)__builtin_bit_cast(u16, fa) | ((u32)__builtin_bit_cast(u16, fb) << 16);
}

// Fused, 2 rows per block, 512 threads (8 waves), 512 blocks.
//  P1: stage s -> LDS once; scan all 1024 candidates vs BOTH rows; compact
//      per-row index lists (u16).
//  P2: per row, 16-pair groups: conv1 f32 VALU -> f16 h1 (double-buffered,
//      ONE barrier/group) -> conv2 v_mfma_f32_16x16x32_f16 (wave w owns
//      channel tile 16w..16w+15; B-frags in 4 VGPR-pairs, loaded once) ->
//      masked max in C-layout -> shfl reduce -> feat.
//  P3: 2-row f32 VALU head + gain epilogue (hidden by inter-block overlap —
//      r7 post-mortem: splitting the head out cost +6.5 us).
__global__ __launch_bounds__(NTH) void NetworkAction_86131274154571_kernel(
    const float* __restrict__ s,    const float* __restrict__ g,
    const float* __restrict__ w1g,  const float* __restrict__ b1g,
    const float* __restrict__ w2g,  const float* __restrict__ b2g,
    const float* __restrict__ fc1w, const float* __restrict__ fc1b,
    const float* __restrict__ fc2w, const float* __restrict__ fc2b,
    const float* __restrict__ fc3w, const float* __restrict__ fc3b,
    const float* __restrict__ fc4w, const float* __restrict__ fc4b,
    float2* __restrict__ out)
{
    __shared__ float4 slds[1024];       // all s rows, staged once
    __shared__ u16    idx[2][1024];     // per-row active-j lists
    __shared__ int    cnt[2];
    __shared__ f16    h1buf[2][16][SH1];// double-buffered conv1 outputs
    __shared__ float  w1s[320];
    __shared__ float  b1s[64];
    __shared__ float  feat[2][132];
    __shared__ float  z1[2][64];
    __shared__ float  z2[2][128];
    __shared__ float  z3[2][64];
    __shared__ float  kk[2][4];

    const int tid  = threadIdx.x;
    const int lane = tid & 63;
    const int wave = tid >> 6;          // 0..7
    const int i0   = blockIdx.x * 2;

    if (tid < 2) cnt[tid] = 0;
    if (tid < 320) w1s[tid] = w1g[tid];
    else if (tid >= 448) b1s[tid - 448] = b1g[tid - 448];

    const float4 si0 = ((const float4*)s)[i0];
    const float4 si1 = ((const float4*)s)[i0 + 1];
    __syncthreads();   // cnt zeroed before pushes

    // ---- P1: stage + dual scan ----
    #pragma unroll
    for (int p = 0; p < 2; ++p) {
        const int j = p * NTH + tid;    // coalesced
        float4 sj = ((const float4*)s)[j];
        slds[j] = sj;
        float dx0 = si0.x - sj.x, dy0 = si0.y - sj.y;
        if (dx0 * dx0 + dy0 * dy0 < 0.25f)
            idx[0][atomicAdd(&cnt[0], 1)] = (u16)j;
        float dx1 = si1.x - sj.x, dy1 = si1.y - sj.y;
        if (dx1 * dx1 + dy1 * dy1 < 0.25f)
            idx[1][atomicAdd(&cnt[1], 1)] = (u16)j;
    }

    // ---- B-frags: wave w owns channels 16w..16w+15 ----
    const int lr = lane & 15;           // channel col in tile / A-row
    const int kq = lane >> 4;           // 0..3
    const int n  = wave * 16 + lr;      // conv2 output channel
    f16x8 bfrag[2];
    {
        #pragma unroll
        for (int t = 0; t < 2; ++t) {
            const float* wp = w2g + n * 64 + t * 32 + kq * 8;
            float4 lo = ((const float4*)wp)[0];
            float4 hi = ((const float4*)wp)[1];
            f16x8 b;
            b[0] = (f16)lo.x; b[1] = (f16)lo.y; b[2] = (f16)lo.z; b[3] = (f16)lo.w;
            b[4] = (f16)hi.x; b[5] = (f16)hi.y; b[6] = (f16)hi.z; b[7] = (f16)hi.w;
            bfrag[t] = b;
        }
    }
    const float b2r = b2g[n];
    __syncthreads();   // slds + idx + cnt ready

    // ---- P2: conv groups, double-buffered, 1 barrier/group ----
    int buf = 0;
    for (int r = 0; r < 2; ++r) {
        const int i_r = i0 + r;
        const float4 si = (r == 0) ? si0 : si1;
        const int nact = cnt[r];
        float m = 0.0f;                 // relu folded into max

        for (int gb = 0; gb < nact; gb += 16) {
            // conv1: 16 pairs x 32 ch-pairs = 512 items, 1/thread
            const int p = tid >> 5, c2 = tid & 31;
            if (gb + p < nact) {
                const int j = idx[r][gb + p];
                const float4 sj = slds[j];   // 32 lanes broadcast same row
                const float x0 = si.x - sj.x, x1 = si.y - sj.y;
                const float x2 = si.z - sj.z, x3 = si.w - sj.w;
                const float x4 = (j == i_r) ? 1.0f : 0.0f;
                const int c = c2 * 2;
                const float* wa = &w1s[c * 5];
                float ha = b1s[c];
                ha = fmaf(wa[0], x0, ha); ha = fmaf(wa[1], x1, ha);
                ha = fmaf(wa[2], x2, ha); ha = fmaf(wa[3], x3, ha);
                ha = fmaf(wa[4], x4, ha);
                const float* wb = &w1s[c * 5 + 5];
                float hb = b1s[c + 1];
                hb = fmaf(wb[0], x0, hb); hb = fmaf(wb[1], x1, hb);
                hb = fmaf(wb[2], x2, hb); hb = fmaf(wb[3], x3, hb);
                hb = fmaf(wb[4], x4, hb);
                *(u32*)&h1buf[buf][p][c2 * 2] = pack2(fmaxf(ha, 0.0f), fmaxf(hb, 0.0f));
            }
            __syncthreads();   // the only barrier this group

            f16x8 a0 = *(const f16x8*)&h1buf[buf][lr][kq * 8];
            f16x8 a1 = *(const f16x8*)&h1buf[buf][lr][32 + kq * 8];
            f32x4 acc = {0.0f, 0.0f, 0.0f, 0.0f};
            acc = __builtin_amdgcn_mfma_f32_16x16x32_f16(a0, bfrag[0], acc, 0, 0, 0);
            acc = __builtin_amdgcn_mfma_f32_16x16x32_f16(a1, bfrag[1], acc, 0, 0, 0);
            #pragma unroll
            for (int rs = 0; rs < 4; ++rs) {
                const bool valid = (gb + kq * 4 + rs) < nact;
                const float v = acc[rs] + b2r;
                m = valid ? fmaxf(m, v) : m;
            }
            buf ^= 1;   // continuous parity: write(g+2) fenced by barrier(g+1)
        }

        // reduce across kq quads (same channel col)
        m = fmaxf(m, __shfl_xor(m, 16));
        m = fmaxf(m, __shfl_xor(m, 32));
        if (lane < 16) feat[r][n] = m;   // n = wave*16 + lane here (lr==lane)
    }

    if (tid < 2) {
        const int i_r = i0 + tid;
        const float4 sv = (tid == 0) ? si0 : si1;
        float2 gv = ((const float2*)g)[i_r];
        feat[tid][128] = sv.x - gv.x;
        feat[tid][129] = sv.y - gv.y;
        feat[tid][130] = sv.z;
        feat[tid][131] = sv.w;
    }
    __syncthreads();

    // ---- P3: 2-row f32 head ----
    if (tid < 128) {                     // fc1: 132 -> 64, rows x ch
        const int row = tid >> 6, c = tid & 63;
        float acc = fc1b[c];
        const float4* wv = (const float4*)(fc1w + c * 132);
        #pragma unroll
        for (int q = 0; q < 33; ++q) {
            float4 u = wv[q];
            int k = q * 4;
            acc = fmaf(u.x, feat[row][k+0], acc);
            acc = fmaf(u.y, feat[row][k+1], acc);
            acc = fmaf(u.z, feat[row][k+2], acc);
            acc = fmaf(u.w, feat[row][k+3], acc);
        }
        z1[row][c] = fmaxf(acc, 0.0f);
    }
    __syncthreads();

    if (tid < 256) {                     // fc2: 64 -> 128
        const int row = tid >> 7, c = tid & 127;
        float acc = fc2b[c];
        const float4* wv = (const float4*)(fc2w + c * 64);
        #pragma unroll
        for (int q = 0; q < 16; ++q) {
            float4 u = wv[q];
            int k = q * 4;
            acc = fmaf(u.x, z1[row][k+0], acc);
            acc = fmaf(u.y, z1[row][k+1], acc);
            acc = fmaf(u.z, z1[row][k+2], acc);
            acc = fmaf(u.w, z1[row][k+3], acc);
        }
        z2[row][c] = fmaxf(acc, 0.0f);
    }
    __syncthreads();

    if (tid < 128) {                     // fc3: 128 -> 64
        const int row = tid >> 6, c = tid & 63;
        float acc = fc3b[c];
        const float4* wv = (const float4*)(fc3w + c * 128);
        #pragma unroll
        for (int q = 0; q < 32; ++q) {
            float4 u = wv[q];
            int k = q * 4;
            acc = fmaf(u.x, z2[row][k+0], acc);
            acc = fmaf(u.y, z2[row][k+1], acc);
            acc = fmaf(u.z, z2[row][k+2], acc);
            acc = fmaf(u.w, z2[row][k+3], acc);
        }
        z3[row][c] = fmaxf(acc, 0.0f);
    }
    __syncthreads();

    if (tid < 8) {                       // fc4: 64 -> 4 + sigmoid gain
        const int row = tid >> 2, mi = tid & 3;
        float acc = fc4b[mi];
        const float4* wv = (const float4*)(fc4w + mi * 64);
        #pragma unroll
        for (int q = 0; q < 16; ++q) {
            float4 u = wv[q];
            int k = q * 4;
            acc = fmaf(u.x, z3[row][k+0], acc);
            acc = fmaf(u.y, z3[row][k+1], acc);
            acc = fmaf(u.z, z3[row][k+2], acc);
            acc = fmaf(u.w, z3[row][k+3], acc);
        }
        kk[row][mi] = 2.0f / (1.0f + expf(-acc)) - 1.0f;
    }
    __syncthreads();

    if (tid < 2) {
        float ax = -(kk[tid][0] * feat[tid][128] + kk[tid][1] * feat[tid][130]);
        float ay = -(kk[tid][2] * feat[tid][129] + kk[tid][3] * feat[tid][131]);
        out[i0 + tid] = make_float2(ax, ay);
    }
}

extern "C" void kernel_launch(void* const* d_in, const int* in_sizes, int n_in,
                              void* d_out, int out_size, void* d_ws, size_t ws_size,
                              hipStream_t stream) {
    const float* s    = (const float*)d_in[0];
    const float* g    = (const float*)d_in[1];
    const float* c1w  = (const float*)d_in[2];
    const float* c1b  = (const float*)d_in[3];
    const float* c2w  = (const float*)d_in[4];
    const float* c2b  = (const float*)d_in[5];
    const float* fc1w = (const float*)d_in[6];
    const float* fc1b = (const float*)d_in[7];
    const float* fc2w = (const float*)d_in[8];
    const float* fc2b = (const float*)d_in[9];
    const float* fc3w = (const float*)d_in[10];
    const float* fc3b = (const float*)d_in[11];
    const float* fc4w = (const float*)d_in[12];
    const float* fc4b = (const float*)d_in[13];

    float2* out = (float2*)d_out;

    NetworkAction_86131274154571_kernel<<<512, NTH, 0, stream>>>(
        s, g, c1w, c1b, c2w, c2b, fc1w, fc1b, fc2w, fc2b,
        fc3w, fc3b, fc4w, fc4b, out);
}